// Round 6
// baseline (140.005 us; speedup 1.0000x reference)
//
#include <hip/hip_runtime.h>
#include <hip/hip_bf16.h>
#include <stdint.h>

// ---------------------------------------------------------------------------
// SupervisedInfoNCELoss, N=8192, D=128, TAF=0.05
// loss = mean_i [ ln(sum_j exp2(acc_ij)) - diag_i ]   where
//   acc_ij = (zn_i * LOG2E/TAF) . bn_j   (A pre-scaled at normalize time)
//   ln(Σ exp2(acc)) == 20 + ln(Σ exp(logit-20))  algebraically (no overflow:
//   max term 2^28.85, sum <= 7.9e12 << f32 max).
// Inner loop per logit = 1 exp2 + 1 add (fma/offset folded away).
//
// Round 6: 8 waves/block (512 rows) = m201's working wave-count quadrant
// (m232: 4-wave phase schedules are null). Phase schedule per 64-col tile:
//   phi0: vmcnt(1); barrier; ds_read jsub0; stage groups{0,1} of next tile
//   phi1: barrier; ds_read jsub1
//   phi2: vmcnt(1); barrier; ds_read jsub2; stage groups{2,3} of next tile
//   phi3: barrier; ds_read jsub3
// Each stage event = 512 threads x 16B = 8KB = 2 chunk-groups; vmcnt(1)
// retires exactly the event holding the group about to be read.
// ---------------------------------------------------------------------------

#define TAF_F 0.05f
constexpr float LOG2E  = 1.4426950408889634f;
constexpr float SCALE  = LOG2E / TAF_F;     // folded into znb at normalize

constexpr int N_ROWS     = 8192;
constexpr int D_DIM      = 128;
constexpr int TWO_N      = 16384;
constexpr int NJ         = 32;              // column chunks
constexpr int JCHUNK     = TWO_N / NJ;      // 512 columns per block
constexpr int BN_TILE    = 64;              // j-tile staged in LDS
constexpr int NT         = JCHUNK / BN_TILE;// 8 tiles per block
constexpr int BLOCK_ROWS = 512;             // rows per block (8 waves x 64)
constexpr int WAVE_ROWS  = 64;              // rows per wave (4 strips of 16)
constexpr int TILE_BYTES = BN_TILE * D_DIM * 2;  // 16 KiB

typedef __bf16 bf16x8 __attribute__((ext_vector_type(8)));
typedef __bf16 bf16x2 __attribute__((ext_vector_type(2)));
typedef float  f32x4  __attribute__((ext_vector_type(4)));

typedef __attribute__((address_space(3))) uint32_t       lds_u32;
typedef const __attribute__((address_space(1))) uint32_t glb_u32;

#if __has_builtin(__builtin_amdgcn_exp2f)
#define EXP2(x) __builtin_amdgcn_exp2f(x)
#else
#define EXP2(x) exp2f(x)
#endif

// ---------------------------------------------------------------------------
// Kernel 1: per-row normalize -> bf16 (A side pre-scaled by LOG2E/TAF),
// plus exact f32 diagonal logit. One wave per row; 4 rows per 256-thr block.
// ---------------------------------------------------------------------------
__global__ void normalize_diag_kernel(const float* __restrict__ z,
                                      const float* __restrict__ zp,
                                      const float* __restrict__ znm,
                                      __bf16* __restrict__ znb,
                                      __bf16* __restrict__ bnb,
                                      float* __restrict__ diag) {
    const int wv   = threadIdx.x >> 6;
    const int lane = threadIdx.x & 63;
    const int i    = blockIdx.x * 4 + wv;

    const float2 vz = *reinterpret_cast<const float2*>(z   + (size_t)i * D_DIM + lane * 2);
    const float2 vp = *reinterpret_cast<const float2*>(zp  + (size_t)i * D_DIM + lane * 2);
    const float2 vn = *reinterpret_cast<const float2*>(znm + (size_t)i * D_DIM + lane * 2);

    float sz  = vz.x * vz.x + vz.y * vz.y;
    float sp  = vp.x * vp.x + vp.y * vp.y;
    float sn  = vn.x * vn.x + vn.y * vn.y;
    float szp = vz.x * vp.x + vz.y * vp.y;
#pragma unroll
    for (int o = 32; o >= 1; o >>= 1) {
        sz  += __shfl_xor(sz, o);
        sp  += __shfl_xor(sp, o);
        sn  += __shfl_xor(sn, o);
        szp += __shfl_xor(szp, o);
    }
    const float rz = SCALE / fmaxf(sqrtf(sz), 1e-8f);   // pre-scaled A
    const float rp = 1.0f / fmaxf(sqrtf(sp), 1e-8f);
    const float rn = 1.0f / fmaxf(sqrtf(sn), 1e-8f);

    bf16x2 oz = { (__bf16)(vz.x * rz), (__bf16)(vz.y * rz) };
    bf16x2 op = { (__bf16)(vp.x * rp), (__bf16)(vp.y * rp) };
    bf16x2 on = { (__bf16)(vn.x * rn), (__bf16)(vn.y * rn) };
    *reinterpret_cast<bf16x2*>(znb + (size_t)i * D_DIM + lane * 2)            = oz;
    *reinterpret_cast<bf16x2*>(bnb + (size_t)i * D_DIM + lane * 2)            = op;
    *reinterpret_cast<bf16x2*>(bnb + (size_t)(N_ROWS + i) * D_DIM + lane * 2) = on;
    if (lane == 0) {
        const float rz0 = 1.0f / fmaxf(sqrtf(sz), 1e-8f);
        diag[i] = szp * rz0 * rp * (1.0f / TAF_F);
    }
}

// ---------------------------------------------------------------------------
// Kernel 2: fused GEMM + partial sum-of-exp2. 8 waves x 64 rows = 512 rows
// per block; grid = 16 x 32 = 512 (XCD-swizzled). 2 x 16KiB LDS buffers,
// counted-vmcnt phase schedule (see header). Staging: linear LDS dest,
// XOR-swizzled global source (chunk g = s ^ ((s>>4)&7)); ds_read applies
// the same involution. mfma_f32_16x16x32_bf16: C row=(lane>>4)*4+reg,
// col=lane&15 (m89).
// ---------------------------------------------------------------------------
__global__ __launch_bounds__(512, 4) void partial_lse_kernel(
        const __bf16* __restrict__ znb,
        const __bf16* __restrict__ bnb,
        float* __restrict__ partial) {
    __shared__ __align__(16) unsigned char lds[TILE_BYTES * 2];  // 32 KiB

    const int tid  = threadIdx.x;          // 0..511
    const int lane = tid & 63;
    const int wv   = tid >> 6;             // 0..7
    const int l15  = lane & 15;
    const int l4   = lane >> 4;

    // T1 XCD swizzle (bijective, 512 % 8 == 0): XCD k -> jChunk in [4k,4k+4)
    const int bid = blockIdx.x;
    const int swz = (bid & 7) * 64 + (bid >> 3);
    const int rowBlk = swz & 15;
    const int jChunk = swz >> 4;
    const int rowBase = rowBlk * BLOCK_ROWS + wv * WAVE_ROWS;
    const int jBase   = jChunk * JCHUNK;

    const unsigned char* srcBase = reinterpret_cast<const unsigned char*>(bnb);

    // stage HALF a tile (2 chunk-groups = 8KB): 512 threads x one 16B DMA
    auto stageHalf = [&](int tile, int buf, int half) {
        const unsigned char* srcTile = srcBase + (size_t)(jBase + tile * BN_TILE) * 256;
        const int s = half * 512 + tid;        // linear 16B-chunk in LDS
        const int g = s ^ ((s >> 4) & 7);      // swizzled source chunk
        __builtin_amdgcn_global_load_lds(
            (glb_u32*)(srcTile + (size_t)g * 16),
            (lds_u32*)(lds + buf * TILE_BYTES + s * 16), 16, 0, 0);
    };

    // A fragments: 4 row-strips x 4 K-steps, held in VGPRs the whole kernel.
    bf16x8 a[4][4];
#pragma unroll
    for (int s = 0; s < 4; ++s)
#pragma unroll
        for (int kk = 0; kk < 4; ++kk) {
            const __bf16* p = znb + (size_t)(rowBase + s * 16 + l15) * D_DIM + kk * 32 + l4 * 8;
            a[s][kk] = *reinterpret_cast<const bf16x8*>(p);
        }

    float sums[4][4];
#pragma unroll
    for (int s = 0; s < 4; ++s)
#pragma unroll
        for (int e = 0; e < 4; ++e) sums[s][e] = 0.0f;

    // prologue: stage both halves of tile 0 into buffer 0 (2 events)
    stageHalf(0, 0, 0);
    stageHalf(0, 0, 1);

    for (int jt = 0; jt < NT; ++jt) {
        const int cur = jt & 1;
        const unsigned char* ldsr = lds + cur * TILE_BYTES;
        const int nxtTile = (jt + 1) & (NT - 1);   // wrap: dead loads, uniform
        const int nxtBuf  = cur ^ 1;
#pragma unroll
        for (int j = 0; j < 4; ++j) {
            if ((j & 1) == 0) {
                // retire the event holding group j (and j+1); keep 1 in flight
                asm volatile("s_waitcnt vmcnt(1)" ::: "memory");
            }
            __builtin_amdgcn_s_barrier();
            __builtin_amdgcn_sched_barrier(0);   // pin ds_reads below barrier

            bf16x8 b[4];
            const int r = j * 16 + l15;          // tile row = output column
#pragma unroll
            for (int kk = 0; kk < 4; ++kk) {
                const int cl = r * 16 + kk * 4 + l4;
                const int ca = cl ^ (r & 7);
                b[kk] = *reinterpret_cast<const bf16x8*>(ldsr + ca * 16);
            }

            if ((j & 1) == 0)
                stageHalf(nxtTile, nxtBuf, j >> 1);  // 1 DMA per thread

            __builtin_amdgcn_s_setprio(1);
#pragma unroll
            for (int s = 0; s < 4; ++s) {
                f32x4 acc = {0.0f, 0.0f, 0.0f, 0.0f};
#pragma unroll
                for (int kk = 0; kk < 4; ++kk)
                    acc = __builtin_amdgcn_mfma_f32_16x16x32_bf16(a[s][kk], b[kk], acc, 0, 0, 0);
#pragma unroll
                for (int e = 0; e < 4; ++e)
                    sums[s][e] += EXP2(acc[e]);      // 1 trans + 1 add only
            }
            __builtin_amdgcn_s_setprio(0);
        }
    }
    // drain the dead wrap-around loads before endpgm
    asm volatile("s_waitcnt vmcnt(0)" ::: "memory");

    // reduce each running sum over the 16 column-holding lanes (lane&15)
#pragma unroll
    for (int s = 0; s < 4; ++s)
#pragma unroll
        for (int e = 0; e < 4; ++e) {
            float v = sums[s][e];
            v += __shfl_xor(v, 1);
            v += __shfl_xor(v, 2);
            v += __shfl_xor(v, 4);
            v += __shfl_xor(v, 8);
            sums[s][e] = v;
        }
    if (l15 == 0) {
#pragma unroll
        for (int s = 0; s < 4; ++s)
#pragma unroll
            for (int e = 0; e < 4; ++e) {
                const int row = rowBase + s * 16 + l4 * 4 + e;
                partial[(size_t)row * NJ + jChunk] = sums[s][e];
            }
    }
}

// ---------------------------------------------------------------------------
// Kernel 3: per-row merge + ln + diag subtract; per-block partial sums.
// lse = ln(se) exactly (the 2^OFFSET factor and +20 cancel algebraically).
// ---------------------------------------------------------------------------
__global__ void finalize_rows_kernel(const float* __restrict__ partial,
                                     const float* __restrict__ diag,
                                     float* __restrict__ blocksum) {
    const int t = threadIdx.x;
    const int r = blockIdx.x * 256 + t;
    const float4* prow = reinterpret_cast<const float4*>(partial + (size_t)r * NJ);
    float se = 0.0f;
#pragma unroll
    for (int c = 0; c < NJ / 4; ++c) {
        const float4 v = prow[c];
        se += (v.x + v.y) + (v.z + v.w);
    }
    float res = logf(se) - diag[r];
#pragma unroll
    for (int o = 32; o >= 1; o >>= 1) res += __shfl_xor(res, o);
    __shared__ float red[4];
    if ((t & 63) == 0) red[t >> 6] = res;
    __syncthreads();
    if (t == 0) blocksum[blockIdx.x] = red[0] + red[1] + red[2] + red[3];
}

// ---------------------------------------------------------------------------
// Kernel 4: final reduce of 32 block sums -> mean -> d_out[0].
// ---------------------------------------------------------------------------
__global__ void final_kernel(const float* __restrict__ blocksum,
                             float* __restrict__ out) {
    const int t = threadIdx.x;  // 64 threads
    float v = (t < 32) ? blocksum[t] : 0.0f;
#pragma unroll
    for (int o = 32; o >= 1; o >>= 1) v += __shfl_xor(v, o);
    if (t == 0) out[0] = v * (1.0f / (float)N_ROWS);
}

// ---------------------------------------------------------------------------
extern "C" void kernel_launch(void* const* d_in, const int* in_sizes, int n_in,
                              void* d_out, int out_size, void* d_ws, size_t ws_size,
                              hipStream_t stream) {
    const float* z   = (const float*)d_in[0];
    const float* zp  = (const float*)d_in[1];
    const float* znm = (const float*)d_in[2];

    char* ws = (char*)d_ws;
    // workspace layout (bytes):
    //   znb     : [8192][128] bf16            @ 0         (2,097,152)
    //   bnb     : [16384][128] bf16           @ 2,097,152 (4,194,304)
    //   diag    : [8192] f32                  @ 6,291,456 (32,768)
    //   partial : [8192][NJ=32] f32           @ 6,324,224 (1,048,576)
    //   blocksum: [32] f32                    @ 7,372,800 (128)
    __bf16* znb     = (__bf16*)(ws);
    __bf16* bnb     = (__bf16*)(ws + 2097152);
    float*  diag    = (float*)(ws + 6291456);
    float*  partial = (float*)(ws + 6324224);
    float*  blocksum= (float*)(ws + 7372800);
    float*  out     = (float*)d_out;

    normalize_diag_kernel<<<N_ROWS / 4, 256, 0, stream>>>(z, zp, znm, znb, bnb, diag);
    partial_lse_kernel<<<NJ * (N_ROWS / BLOCK_ROWS), 512, 0, stream>>>(znb, bnb, partial);
    finalize_rows_kernel<<<N_ROWS / 256, 256, 0, stream>>>(partial, diag, blocksum);
    final_kernel<<<1, 64, 0, stream>>>(blocksum, out);
}

// Round 7
// 58.234 us; speedup vs baseline: 2.4042x; 2.4042x over previous
//
#include <hip/hip_runtime.h>
#include <hip/hip_bf16.h>
#include <stdint.h>

// ---------------------------------------------------------------------------
// SupervisedInfoNCELoss, N=8192, D=128, TAF=0.05
// loss = mean_i [ ln(sum_j exp2(acc_ij)) - diag_i ]   where
//   acc_ij = (zn_i * LOG2E/TAF) . bn_j   (A pre-scaled at normalize time)
//   ln(Σ exp2(acc)) == 20 + ln(Σ exp(logit-20))  algebraically (no overflow:
//   max term 2^28.85, sum <= 7.9e12 << f32 max). Validated round 6 (absmax 0).
//
// Round 7: BARRIER-FREE 1-wave blocks. Round-5 counters showed dur ~= SUM of
// {VALU 19us, MFMA 14us, LDS 13.6us} pipes -- block-level barriers convoy all
// waves into the same pipe simultaneously. Now each 64-thread block = 1 wave,
// self-paced: private 2x4KB LDS dbuf, 16-col B tiles, counted vmcnt(4), no
// s_barrier anywhere. 4096 independent waves (16/CU) let pipes overlap.
// NO __launch_bounds__ occupancy cap (rounds 2/6 spill lesson: needs ~110 VGPR).
// ---------------------------------------------------------------------------

#define TAF_F 0.05f
constexpr float LOG2E  = 1.4426950408889634f;
constexpr float SCALE  = LOG2E / TAF_F;     // folded into znb at normalize

constexpr int N_ROWS     = 8192;
constexpr int D_DIM      = 128;
constexpr int TWO_N      = 16384;
constexpr int NJ         = 32;              // column chunks
constexpr int JCHUNK     = TWO_N / NJ;      // 512 columns per wave-block
constexpr int COL_TILE   = 16;              // B tile staged per step
constexpr int NTW        = JCHUNK / COL_TILE;   // 32 tiles per wave
constexpr int WAVE_ROWS  = 64;              // rows per wave (4 strips of 16)
constexpr int ROW_BLOCKS = N_ROWS / WAVE_ROWS;  // 128
constexpr int TILE_BYTES = COL_TILE * D_DIM * 2;  // 4 KiB

typedef __bf16 bf16x8 __attribute__((ext_vector_type(8)));
typedef __bf16 bf16x2 __attribute__((ext_vector_type(2)));
typedef float  f32x4  __attribute__((ext_vector_type(4)));

typedef __attribute__((address_space(3))) uint32_t       lds_u32;
typedef const __attribute__((address_space(1))) uint32_t glb_u32;

#if __has_builtin(__builtin_amdgcn_exp2f)
#define EXP2(x) __builtin_amdgcn_exp2f(x)
#else
#define EXP2(x) exp2f(x)
#endif

// ---------------------------------------------------------------------------
// Kernel 1: per-row normalize -> bf16 (A side pre-scaled by LOG2E/TAF),
// plus exact f32 diagonal logit. One wave per row; 4 rows per 256-thr block.
// ---------------------------------------------------------------------------
__global__ void normalize_diag_kernel(const float* __restrict__ z,
                                      const float* __restrict__ zp,
                                      const float* __restrict__ znm,
                                      __bf16* __restrict__ znb,
                                      __bf16* __restrict__ bnb,
                                      float* __restrict__ diag) {
    const int wv   = threadIdx.x >> 6;
    const int lane = threadIdx.x & 63;
    const int i    = blockIdx.x * 4 + wv;

    const float2 vz = *reinterpret_cast<const float2*>(z   + (size_t)i * D_DIM + lane * 2);
    const float2 vp = *reinterpret_cast<const float2*>(zp  + (size_t)i * D_DIM + lane * 2);
    const float2 vn = *reinterpret_cast<const float2*>(znm + (size_t)i * D_DIM + lane * 2);

    float sz  = vz.x * vz.x + vz.y * vz.y;
    float sp  = vp.x * vp.x + vp.y * vp.y;
    float sn  = vn.x * vn.x + vn.y * vn.y;
    float szp = vz.x * vp.x + vz.y * vp.y;
#pragma unroll
    for (int o = 32; o >= 1; o >>= 1) {
        sz  += __shfl_xor(sz, o);
        sp  += __shfl_xor(sp, o);
        sn  += __shfl_xor(sn, o);
        szp += __shfl_xor(szp, o);
    }
    const float rz = SCALE / fmaxf(sqrtf(sz), 1e-8f);   // pre-scaled A
    const float rp = 1.0f / fmaxf(sqrtf(sp), 1e-8f);
    const float rn = 1.0f / fmaxf(sqrtf(sn), 1e-8f);

    bf16x2 oz = { (__bf16)(vz.x * rz), (__bf16)(vz.y * rz) };
    bf16x2 op = { (__bf16)(vp.x * rp), (__bf16)(vp.y * rp) };
    bf16x2 on = { (__bf16)(vn.x * rn), (__bf16)(vn.y * rn) };
    *reinterpret_cast<bf16x2*>(znb + (size_t)i * D_DIM + lane * 2)            = oz;
    *reinterpret_cast<bf16x2*>(bnb + (size_t)i * D_DIM + lane * 2)            = op;
    *reinterpret_cast<bf16x2*>(bnb + (size_t)(N_ROWS + i) * D_DIM + lane * 2) = on;
    if (lane == 0) {
        const float rz0 = 1.0f / fmaxf(sqrtf(sz), 1e-8f);
        diag[i] = szp * rz0 * rp * (1.0f / TAF_F);
    }
}

// ---------------------------------------------------------------------------
// Kernel 2: fused GEMM + partial sum-of-exp2. ONE WAVE PER BLOCK, no barriers.
// grid = ROW_BLOCKS x NJ = 4096 blocks of 64 threads (XCD-swizzled).
// Per block: 64 rows (a[4][4] in VGPRs) x 512 cols in 32 tiles of 16 cols.
// LDS: 2 x 4KB dbuf. Per tile: issue 4 gload_lds DMAs for t+1, vmcnt(4)
// retires exactly tile t's DMAs, then 4 ds_read_b128 + 16 MFMA + 16 exp2.
// Staging: linear LDS dest, XOR-swizzled global source (g = s ^ ((s>>4)&7));
// ds_read applies the same involution. mfma_f32_16x16x32_bf16:
// C row=(lane>>4)*4+reg, col=lane&15 (m89).
// ---------------------------------------------------------------------------
__global__ __launch_bounds__(64) void partial_lse_kernel(
        const __bf16* __restrict__ znb,
        const __bf16* __restrict__ bnb,
        float* __restrict__ partial) {
    __shared__ __align__(16) unsigned char lds[TILE_BYTES * 2];  // 8 KiB

    const int lane = threadIdx.x;          // 0..63
    const int l15  = lane & 15;
    const int l4   = lane >> 4;

    // T1 XCD swizzle (bijective, 4096 % 8 == 0): XCD k -> 4 contiguous
    // jChunks -> 512KB of bnb + znb per XCD L2.
    const int bid = blockIdx.x;
    const int swz = (bid & 7) * (4096 / 8) + (bid >> 3);
    const int rowBlk = swz & (ROW_BLOCKS - 1);
    const int jChunk = swz >> 7;           // swz / ROW_BLOCKS
    const int rowBase = rowBlk * WAVE_ROWS;
    const int jBase   = jChunk * JCHUNK;

    const unsigned char* srcBase = reinterpret_cast<const unsigned char*>(bnb);

    // stage one 16-col tile (4KB = 256 x 16B chunks): 64 threads x 4 DMAs
    auto stageTile = [&](int tile, int buf) {
        const unsigned char* srcTile = srcBase + (size_t)(jBase + tile * COL_TILE) * 256;
        unsigned char* ldsw = lds + buf * TILE_BYTES;
#pragma unroll
        for (int it = 0; it < 4; ++it) {
            const int s = it * 64 + lane;          // linear 16B-chunk in LDS
            const int g = s ^ ((s >> 4) & 7);      // swizzled source chunk
            __builtin_amdgcn_global_load_lds(
                (glb_u32*)(srcTile + (size_t)g * 16),
                (lds_u32*)(ldsw + s * 16), 16, 0, 0);
        }
    };

    // A fragments: 4 row-strips x 4 K-steps, held in VGPRs the whole kernel.
    bf16x8 a[4][4];
#pragma unroll
    for (int s = 0; s < 4; ++s)
#pragma unroll
        for (int kk = 0; kk < 4; ++kk) {
            const __bf16* p = znb + (size_t)(rowBase + s * 16 + l15) * D_DIM + kk * 32 + l4 * 8;
            a[s][kk] = *reinterpret_cast<const bf16x8*>(p);
        }

    float sums[4][4];
#pragma unroll
    for (int s = 0; s < 4; ++s)
#pragma unroll
        for (int e = 0; e < 4; ++e) sums[s][e] = 0.0f;

    stageTile(0, 0);   // prologue

    for (int t = 0; t < NTW; ++t) {
        // issue next tile's 4 DMAs (wrap at end: dead but uniform accounting)
        stageTile((t + 1) & (NTW - 1), (t + 1) & 1);
        // retire exactly tile t's 4 DMAs; keep tile t+1's 4 in flight
        asm volatile("s_waitcnt vmcnt(4)" ::: "memory");

        const unsigned char* ldsr = lds + (t & 1) * TILE_BYTES;
        bf16x8 b[4];
#pragma unroll
        for (int kk = 0; kk < 4; ++kk) {
            const int cl = l15 * 16 + kk * 4 + l4;   // row = l15
            const int ca = cl ^ (l15 & 7);           // same involution
            b[kk] = *reinterpret_cast<const bf16x8*>(ldsr + ca * 16);
        }
#pragma unroll
        for (int s = 0; s < 4; ++s) {
            f32x4 acc = {0.0f, 0.0f, 0.0f, 0.0f};
#pragma unroll
            for (int kk = 0; kk < 4; ++kk)
                acc = __builtin_amdgcn_mfma_f32_16x16x32_bf16(a[s][kk], b[kk], acc, 0, 0, 0);
#pragma unroll
            for (int e = 0; e < 4; ++e)
                sums[s][e] += EXP2(acc[e]);          // 1 trans + 1 add
        }
    }
    // drain the dead wrap-around DMAs before block exit
    asm volatile("s_waitcnt vmcnt(0)" ::: "memory");

    // reduce each running sum over the 16 column-holding lanes (lane&15)
#pragma unroll
    for (int s = 0; s < 4; ++s)
#pragma unroll
        for (int e = 0; e < 4; ++e) {
            float v = sums[s][e];
            v += __shfl_xor(v, 1);
            v += __shfl_xor(v, 2);
            v += __shfl_xor(v, 4);
            v += __shfl_xor(v, 8);
            sums[s][e] = v;
        }
    if (l15 == 0) {
#pragma unroll
        for (int s = 0; s < 4; ++s)
#pragma unroll
            for (int e = 0; e < 4; ++e) {
                const int row = rowBase + s * 16 + l4 * 4 + e;
                partial[(size_t)row * NJ + jChunk] = sums[s][e];
            }
    }
}

// ---------------------------------------------------------------------------
// Kernel 3: per-row merge + ln + diag subtract; per-block partial sums.
// lse = ln(se) exactly (the 2^OFFSET factor and +20 cancel algebraically).
// ---------------------------------------------------------------------------
__global__ void finalize_rows_kernel(const float* __restrict__ partial,
                                     const float* __restrict__ diag,
                                     float* __restrict__ blocksum) {
    const int t = threadIdx.x;
    const int r = blockIdx.x * 256 + t;
    const float4* prow = reinterpret_cast<const float4*>(partial + (size_t)r * NJ);
    float se = 0.0f;
#pragma unroll
    for (int c = 0; c < NJ / 4; ++c) {
        const float4 v = prow[c];
        se += (v.x + v.y) + (v.z + v.w);
    }
    float res = logf(se) - diag[r];
#pragma unroll
    for (int o = 32; o >= 1; o >>= 1) res += __shfl_xor(res, o);
    __shared__ float red[4];
    if ((t & 63) == 0) red[t >> 6] = res;
    __syncthreads();
    if (t == 0) blocksum[blockIdx.x] = red[0] + red[1] + red[2] + red[3];
}

// ---------------------------------------------------------------------------
// Kernel 4: final reduce of 32 block sums -> mean -> d_out[0].
// ---------------------------------------------------------------------------
__global__ void final_kernel(const float* __restrict__ blocksum,
                             float* __restrict__ out) {
    const int t = threadIdx.x;  // 64 threads
    float v = (t < 32) ? blocksum[t] : 0.0f;
#pragma unroll
    for (int o = 32; o >= 1; o >>= 1) v += __shfl_xor(v, o);
    if (t == 0) out[0] = v * (1.0f / (float)N_ROWS);
}

// ---------------------------------------------------------------------------
extern "C" void kernel_launch(void* const* d_in, const int* in_sizes, int n_in,
                              void* d_out, int out_size, void* d_ws, size_t ws_size,
                              hipStream_t stream) {
    const float* z   = (const float*)d_in[0];
    const float* zp  = (const float*)d_in[1];
    const float* znm = (const float*)d_in[2];

    char* ws = (char*)d_ws;
    // workspace layout (bytes):
    //   znb     : [8192][128] bf16            @ 0         (2,097,152)
    //   bnb     : [16384][128] bf16           @ 2,097,152 (4,194,304)
    //   diag    : [8192] f32                  @ 6,291,456 (32,768)
    //   partial : [8192][NJ=32] f32           @ 6,324,224 (1,048,576)
    //   blocksum: [32] f32                    @ 7,372,800 (128)
    __bf16* znb     = (__bf16*)(ws);
    __bf16* bnb     = (__bf16*)(ws + 2097152);
    float*  diag    = (float*)(ws + 6291456);
    float*  partial = (float*)(ws + 6324224);
    float*  blocksum= (float*)(ws + 7372800);
    float*  out     = (float*)d_out;

    normalize_diag_kernel<<<N_ROWS / 4, 256, 0, stream>>>(z, zp, znm, znb, bnb, diag);
    partial_lse_kernel<<<ROW_BLOCKS * NJ, 64, 0, stream>>>(znb, bnb, partial);
    finalize_rows_kernel<<<N_ROWS / 256, 256, 0, stream>>>(partial, diag, blocksum);
    final_kernel<<<1, 64, 0, stream>>>(blocksum, out);
}

// Round 8
// 53.905 us; speedup vs baseline: 2.5972x; 1.0803x over previous
//
#include <hip/hip_runtime.h>
#include <hip/hip_bf16.h>
#include <stdint.h>

// ---------------------------------------------------------------------------
// SupervisedInfoNCELoss, N=8192, D=128, TAF=0.05
// loss = mean_i [ ln(sum_j exp2(acc_ij)) - diag_i ]   where
//   acc_ij = (zn_i * LOG2E/TAF) . bn_j   in fp8-e4m3 x fp8-e4m3 MFMA
//   diag_i computed EXACTLY in f32 (quantization noise only perturbs the lse
//   sum; convexity bias ~0.003 << 0.225 threshold).
//
// Round 8: shrink all pipes. Rounds 1/3/5/7 (4 different schedules) all hit
// 46-50us ~= SUM of {matrix 16.5, trans 13.7, LDS 17, L2 15} us pipe budgets.
// fp8 + mfma_f32_32x32x16_fp8_fp8 halves matrix instrs (13.8us), halves
// operand bytes (LDS ~7us, L2 ~7.4us), conflict-free b64 reads. Trans 13.7us
// is the irreducible floor (1 exp2 per logit). Keep round-7 barrier-free
// self-paced 1-wave structure. NO __launch_bounds__ VGPR cap (r2/r6 lesson).
// ---------------------------------------------------------------------------

#define TAF_F 0.05f
constexpr float LOG2E  = 1.4426950408889634f;
constexpr float SCALE  = LOG2E / TAF_F;     // folded into znb8 at normalize

constexpr int N_ROWS     = 8192;
constexpr int D_DIM      = 128;
constexpr int TWO_N      = 16384;
constexpr int NJ         = 32;              // column chunks
constexpr int JCHUNK     = TWO_N / NJ;      // 512 columns per wave-block
constexpr int COL_TILE   = 32;              // B tile staged per step (32x32 MFMA)
constexpr int NTW        = JCHUNK / COL_TILE;   // 16 tiles per wave
constexpr int WAVE_ROWS  = 64;              // rows per wave (2 strips of 32)
constexpr int ROW_BLOCKS = N_ROWS / WAVE_ROWS;  // 128
constexpr int TILE_BYTES = COL_TILE * D_DIM;    // 4 KiB (fp8)

typedef float  f32x16 __attribute__((ext_vector_type(16)));
typedef __bf16 bf16x2 __attribute__((ext_vector_type(2)));

typedef __attribute__((address_space(3))) uint32_t       lds_u32;
typedef const __attribute__((address_space(1))) uint32_t glb_u32;

#if __has_builtin(__builtin_amdgcn_exp2f)
#define EXP2(x) __builtin_amdgcn_exp2f(x)
#else
#define EXP2(x) exp2f(x)
#endif

// f32 -> OCP e4m3fn, RNE, FTZ below 2^-6 (subnormal contributions are
// negligible here: |lost logit| << quantization noise already budgeted).
__device__ inline unsigned char f32_to_e4m3(float f) {
    unsigned u = __float_as_uint(f);
    unsigned sg = (u >> 24) & 0x80u;
    unsigned au = u & 0x7FFFFFFFu;
    if (au < 0x3C800000u) return (unsigned char)sg;   // |f| < 2^-6 -> +-0
    if (au > 0x43E00000u) au = 0x43E00000u;           // clamp to 448
    const unsigned lsb = (au >> 20) & 1u;
    au += 0x0007FFFFu + lsb;                          // RNE to 3 mantissa bits
    int e = (int)(au >> 23) - 127 + 7;
    unsigned m = (au >> 20) & 7u;
    if (e > 15) { e = 15; m = 6u; }                   // re-clamp to 448
    return (unsigned char)(sg | ((unsigned)e << 3) | m);
}

// ---------------------------------------------------------------------------
// Kernel 1: per-row normalize -> fp8 (A side pre-scaled by LOG2E/TAF),
// plus exact f32 diagonal logit. One wave per row; 4 rows per 256-thr block.
// ---------------------------------------------------------------------------
__global__ void normalize_quant_kernel(const float* __restrict__ z,
                                       const float* __restrict__ zp,
                                       const float* __restrict__ znm,
                                       unsigned char* __restrict__ znb8,
                                       unsigned char* __restrict__ bnb8,
                                       float* __restrict__ diag) {
    const int wv   = threadIdx.x >> 6;
    const int lane = threadIdx.x & 63;
    const int i    = blockIdx.x * 4 + wv;

    const float2 vz = *reinterpret_cast<const float2*>(z   + (size_t)i * D_DIM + lane * 2);
    const float2 vp = *reinterpret_cast<const float2*>(zp  + (size_t)i * D_DIM + lane * 2);
    const float2 vn = *reinterpret_cast<const float2*>(znm + (size_t)i * D_DIM + lane * 2);

    float sz  = vz.x * vz.x + vz.y * vz.y;
    float sp  = vp.x * vp.x + vp.y * vp.y;
    float sn  = vn.x * vn.x + vn.y * vn.y;
    float szp = vz.x * vp.x + vz.y * vp.y;
#pragma unroll
    for (int o = 32; o >= 1; o >>= 1) {
        sz  += __shfl_xor(sz, o);
        sp  += __shfl_xor(sp, o);
        sn  += __shfl_xor(sn, o);
        szp += __shfl_xor(szp, o);
    }
    const float rz0 = 1.0f / fmaxf(sqrtf(sz), 1e-8f);
    const float rzs = rz0 * SCALE;                      // pre-scaled A
    const float rp  = 1.0f / fmaxf(sqrtf(sp), 1e-8f);
    const float rn  = 1.0f / fmaxf(sqrtf(sn), 1e-8f);

    const unsigned short za = (unsigned short)f32_to_e4m3(vz.x * rzs)
                            | ((unsigned short)f32_to_e4m3(vz.y * rzs) << 8);
    const unsigned short pa = (unsigned short)f32_to_e4m3(vp.x * rp)
                            | ((unsigned short)f32_to_e4m3(vp.y * rp) << 8);
    const unsigned short na = (unsigned short)f32_to_e4m3(vn.x * rn)
                            | ((unsigned short)f32_to_e4m3(vn.y * rn) << 8);
    *reinterpret_cast<unsigned short*>(znb8 + (size_t)i * D_DIM + lane * 2)            = za;
    *reinterpret_cast<unsigned short*>(bnb8 + (size_t)i * D_DIM + lane * 2)            = pa;
    *reinterpret_cast<unsigned short*>(bnb8 + (size_t)(N_ROWS + i) * D_DIM + lane * 2) = na;
    if (lane == 0) diag[i] = szp * rz0 * rp * (1.0f / TAF_F);
}

// ---------------------------------------------------------------------------
// Kernel 2: fused fp8 GEMM + partial sum-of-exp2. ONE WAVE PER BLOCK, no
// barriers. grid = 4096 blocks of 64 threads (XCD-swizzled).
// Per block: 64 rows (2 strips of 32; a[2][8] i64 frags in VGPRs) x 512 cols
// in 16 tiles of 32 cols. LDS: 2 x 4KB dbuf; per tile: 4 gload_lds DMAs for
// t+1, vmcnt(4) retires t's, then 8 ds_read_b64 + 16 MFMA + 32 exp2/add.
// LDS layout [col][128B], 16B chunk q swizzled q' = q ^ (col&7): ds_read_b64
// banks (q'*4 + l5*2) -> conflict-free (4-cycle floor met).
// mfma_f32_32x32x16_fp8_fp8: A/B row|col = lane&31, k = (lane>>5)*8+e;
// C/D col = lane&31, row = (reg&3) + 8*(reg>>2) + 4*(lane>>5)  [m74/m101].
// ---------------------------------------------------------------------------
__global__ __launch_bounds__(64) void partial_lse_kernel(
        const unsigned char* __restrict__ znb8,
        const unsigned char* __restrict__ bnb8,
        float* __restrict__ partial) {
    __shared__ __align__(16) unsigned char lds[TILE_BYTES * 2];  // 8 KiB

    const int lane = threadIdx.x;          // 0..63
    const int l31  = lane & 31;
    const int l5   = lane >> 5;

    // T1 XCD swizzle (bijective, 4096 % 8 == 0): XCD k -> 4 contiguous
    // jChunks -> 256KB of bnb8 + 1MB znb8 per XCD L2.
    const int bid = blockIdx.x;
    const int swz = (bid & 7) * (4096 / 8) + (bid >> 3);
    const int rowBlk = swz & (ROW_BLOCKS - 1);
    const int jChunk = swz >> 7;
    const int rowBase = rowBlk * WAVE_ROWS;
    const int jBase   = jChunk * JCHUNK;

    // stage one 32-col tile (4KB = 256 x 16B chunks): 64 threads x 4 DMAs
    auto stageTile = [&](int tile, int buf) {
        const unsigned char* srcTile = bnb8 + (size_t)(jBase + tile * COL_TILE) * D_DIM;
        unsigned char* ldsw = lds + buf * TILE_BYTES;
#pragma unroll
        for (int it = 0; it < 4; ++it) {
            const int s = it * 64 + lane;                      // chunk (col=s>>3, q=s&7)
            const int g = (s & ~7) | ((s & 7) ^ ((s >> 3) & 7));  // src chunk (col, q^(col&7))
            __builtin_amdgcn_global_load_lds(
                (glb_u32*)(srcTile + (size_t)g * 16),
                (lds_u32*)(ldsw + s * 16), 16, 0, 0);
        }
    };

    // A fragments: 2 strips x 8 K-steps, held in VGPRs the whole kernel.
    long a[2][8];
#pragma unroll
    for (int st = 0; st < 2; ++st)
#pragma unroll
        for (int kk = 0; kk < 8; ++kk)
            a[st][kk] = *reinterpret_cast<const long*>(
                znb8 + (size_t)(rowBase + st * 32 + l31) * D_DIM + kk * 16 + l5 * 8);

    float sums[2][16];
#pragma unroll
    for (int st = 0; st < 2; ++st)
#pragma unroll
        for (int e = 0; e < 16; ++e) sums[st][e] = 0.0f;

    stageTile(0, 0);   // prologue

    for (int t = 0; t < NTW; ++t) {
        // issue next tile's 4 DMAs (wrap at end: dead but uniform accounting)
        stageTile((t + 1) & (NTW - 1), (t + 1) & 1);
        // retire exactly tile t's 4 DMAs; keep tile t+1's 4 in flight
        asm volatile("s_waitcnt vmcnt(4)" ::: "memory");

        const unsigned char* ldsr = lds + (t & 1) * TILE_BYTES;
        long b[8];
#pragma unroll
        for (int kk = 0; kk < 8; ++kk) {
            const int q = kk ^ (l31 & 7);                    // swizzled 16B chunk
            b[kk] = *reinterpret_cast<const long*>(ldsr + l31 * D_DIM + q * 16 + l5 * 8);
        }
#pragma unroll
        for (int st = 0; st < 2; ++st) {
            f32x16 acc = {};
#pragma unroll
            for (int kk = 0; kk < 8; ++kk)
                acc = __builtin_amdgcn_mfma_f32_32x32x16_fp8_fp8(a[st][kk], b[kk], acc, 0, 0, 0);
#pragma unroll
            for (int e = 0; e < 16; ++e)
                sums[st][e] += EXP2(acc[e]);                 // 1 trans + 1 add
        }
    }
    // drain the dead wrap-around DMAs before block exit
    asm volatile("s_waitcnt vmcnt(0)" ::: "memory");

    // reduce each sum over the 32 column-holding lanes (lane&31)
#pragma unroll
    for (int st = 0; st < 2; ++st)
#pragma unroll
        for (int e = 0; e < 16; ++e) {
            float v = sums[st][e];
            v += __shfl_xor(v, 1);
            v += __shfl_xor(v, 2);
            v += __shfl_xor(v, 4);
            v += __shfl_xor(v, 8);
            v += __shfl_xor(v, 16);
            sums[st][e] = v;
        }
    if (l31 == 0) {   // lanes 0 and 32 (l5 = 0/1) hold different rows
#pragma unroll
        for (int st = 0; st < 2; ++st)
#pragma unroll
            for (int e = 0; e < 16; ++e) {
                const int row = rowBase + st * 32 + (e & 3) + 8 * (e >> 2) + 4 * l5;
                partial[(size_t)row * NJ + jChunk] = sums[st][e];
            }
    }
}

// ---------------------------------------------------------------------------
// Kernel 3: per-row merge + ln + diag subtract; per-block partial sums.
// lse = ln(se) exactly (fixed-max offset cancels algebraically).
// ---------------------------------------------------------------------------
__global__ void finalize_rows_kernel(const float* __restrict__ partial,
                                     const float* __restrict__ diag,
                                     float* __restrict__ blocksum) {
    const int t = threadIdx.x;
    const int r = blockIdx.x * 256 + t;
    const float4* prow = reinterpret_cast<const float4*>(partial + (size_t)r * NJ);
    float se = 0.0f;
#pragma unroll
    for (int c = 0; c < NJ / 4; ++c) {
        const float4 v = prow[c];
        se += (v.x + v.y) + (v.z + v.w);
    }
    float res = logf(se) - diag[r];
#pragma unroll
    for (int o = 32; o >= 1; o >>= 1) res += __shfl_xor(res, o);
    __shared__ float red[4];
    if ((t & 63) == 0) red[t >> 6] = res;
    __syncthreads();
    if (t == 0) blocksum[blockIdx.x] = red[0] + red[1] + red[2] + red[3];
}

// ---------------------------------------------------------------------------
// Kernel 4: final reduce of 32 block sums -> mean -> d_out[0].
// ---------------------------------------------------------------------------
__global__ void final_kernel(const float* __restrict__ blocksum,
                             float* __restrict__ out) {
    const int t = threadIdx.x;  // 64 threads
    float v = (t < 32) ? blocksum[t] : 0.0f;
#pragma unroll
    for (int o = 32; o >= 1; o >>= 1) v += __shfl_xor(v, o);
    if (t == 0) out[0] = v * (1.0f / (float)N_ROWS);
}

// ---------------------------------------------------------------------------
extern "C" void kernel_launch(void* const* d_in, const int* in_sizes, int n_in,
                              void* d_out, int out_size, void* d_ws, size_t ws_size,
                              hipStream_t stream) {
    const float* z   = (const float*)d_in[0];
    const float* zp  = (const float*)d_in[1];
    const float* znm = (const float*)d_in[2];

    char* ws = (char*)d_ws;
    // workspace layout (bytes):
    //   znb8    : [8192][128] fp8             @ 0         (1,048,576)
    //   bnb8    : [16384][128] fp8            @ 1,048,576 (2,097,152)
    //   diag    : [8192] f32                  @ 3,145,728 (32,768)
    //   partial : [8192][NJ=32] f32           @ 3,178,496 (1,048,576)
    //   blocksum: [32] f32                    @ 4,227,072 (128)
    unsigned char* znb8 = (unsigned char*)(ws);
    unsigned char* bnb8 = (unsigned char*)(ws + 1048576);
    float* diag     = (float*)(ws + 3145728);
    float* partial  = (float*)(ws + 3178496);
    float* blocksum = (float*)(ws + 4227072);
    float* out      = (float*)d_out;

    normalize_quant_kernel<<<N_ROWS / 4, 256, 0, stream>>>(z, zp, znm, znb8, bnb8, diag);
    partial_lse_kernel<<<ROW_BLOCKS * NJ, 64, 0, stream>>>(znb8, bnb8, partial);
    finalize_rows_kernel<<<N_ROWS / 256, 256, 0, stream>>>(partial, diag, blocksum);
    final_kernel<<<1, 64, 0, stream>>>(blocksum, out);
}